// Round 23
// baseline (85.856 us; speedup 1.0000x reference)
//
#include <hip/hip_runtime.h>
#include <hip/hip_bf16.h>

typedef short bf16x8 __attribute__((ext_vector_type(8)));
typedef float f32x4 __attribute__((ext_vector_type(4)));

#define LN_EPS 1e-5f
#define SLOPE 0.2f

// Native conversion: compiler fuses adjacent pairs to v_cvt_pk_bf16_f32 (m240).
__device__ __forceinline__ unsigned short f2bf(float f){
  __hip_bfloat16 b = __float2bfloat16(f);
  return *reinterpret_cast<unsigned short*>(&b);
}

// Verified W image (rounds 1..22):
// wbf[((s*4+g)*512 + c)*8 + j] = W[k = s*32+g*8+j][c]   (c<256: W_l, else W_r)
__global__ void wconv_kernel(const float* __restrict__ Wl,
                             const float* __restrict__ Wr,
                             unsigned short* __restrict__ wbf){
  int idx = blockIdx.x * 256 + threadIdx.x;   // 0..16383 : (s,g,c)
  int c = idx & 511;
  int gg = (idx >> 9) & 3;
  int s = idx >> 11;
  int k0 = s * 32 + gg * 8;
  const float* src = (c < 256) ? (Wl + c) : (Wr + (c - 256));
  bf16x8 v;
  #pragma unroll
  for (int j = 0; j < 8; ++j) v[j] = (short)f2bf(src[(k0 + j) * 256]);
  *(bf16x8*)&wbf[(size_t)idx * 8] = v;
}

// R22 verified base (84.5 us best), single change: __launch_bounds__(256,3).
// minwaves=4 MISCOMPILES (R5/R6: forces <=128 regs, below the kernel's natural
// 148 -> forced acc spill/remat hazard). minwaves=3 caps at 170 — 22 regs ABOVE
// current allocation (84 VGPR + 64 AGPR), so the poison mechanism is absent;
// it only pins the 3-waves/EU target for allocator + scheduler.
// NOTE: persistent/reg-prefetch-across-phases spills (R10,R18); no-LDS A-frags
// latency-bound (R20); kernel split loses to fusion (R16).
template<bool USE_WS>
__global__ __launch_bounds__(256, 3)
void gat_fused(const float* __restrict__ hin, const float* __restrict__ ebias,
               const float* __restrict__ Wl, const float* __restrict__ Wr,
               const float* __restrict__ avec, const float* __restrict__ gmw,
               const float* __restrict__ btw, const unsigned short* __restrict__ wbf,
               float* __restrict__ out){
  __shared__ __align__(16) unsigned short uni[8192];    // h-tile [32][256] bf16, 16KB
  __shared__ float red1[128], red2[128];                // [row][wave] LN partials
  __shared__ float eb_s[16];

  const int t = threadIdx.x;
  const int lane = t & 63;
  const int w = t >> 6;
  const int b0 = blockIdx.x * 8;
  const int g = lane >> 4;
  const int ln = lane & 15;

  float av[4];
  #pragma unroll
  for (int c = 0; c < 4; ++c) av[c] = avec[w * 64 + c * 16 + ln];
  if (t < 16) eb_s[t] = ebias[t];

  // ---- stage h tile (32 rows x 256 k) f32->bf16, XOR-swizzled (verified R4)
  {
    const float* hb = hin + (size_t)b0 * 1024;
    #pragma unroll
    for (int it = 0; it < 4; ++it){
      int q = it * 256 + t;              // 16B-chunk id, 1024 total
      int row = q >> 5;
      int c = q & 31;
      const float* src = hb + row * 256 + c * 8;
      float4 f0 = *(const float4*)src;
      float4 f1 = *(const float4*)(src + 4);
      bf16x8 v;
      v[0]=(short)f2bf(f0.x); v[1]=(short)f2bf(f0.y); v[2]=(short)f2bf(f0.z); v[3]=(short)f2bf(f0.w);
      v[4]=(short)f2bf(f1.x); v[5]=(short)f2bf(f1.y); v[6]=(short)f2bf(f1.z); v[7]=(short)f2bf(f1.w);
      *(bf16x8*)&uni[row * 256 + ((c ^ (row & 7)) << 3)] = v;
    }
  }
  __syncthreads();

  f32x4 acc[2][8];
  #pragma unroll
  for (int m = 0; m < 2; ++m)
    #pragma unroll
    for (int c = 0; c < 8; ++c)
      acc[m][c] = (f32x4){0.f, 0.f, 0.f, 0.f};

  // ---- pipelined K loop, full-step prefetch for P and Q (R22 verbatim)
  if constexpr (USE_WS){
    const unsigned short* wbase = wbf + (size_t)g * 4096 + (size_t)(w * 64 + ln) * 8;
    bf16x8 af[2], afn[2], P[4], Q[4], Pn[4], Qn[4];
    #pragma unroll
    for (int m = 0; m < 2; ++m)
      af[m] = *(const bf16x8*)&uni[(m * 16 + ln) * 256 + ((g ^ (ln & 7)) << 3)];
    #pragma unroll
    for (int c = 0; c < 4; ++c){
      P[c] = *(const bf16x8*)(wbase + c * 128);           // gl(0)
      Q[c] = *(const bf16x8*)(wbase + 2048 + c * 128);    // gr(0)
    }

    #pragma unroll
    for (int step = 0; step < 8; ++step){
      if (step < 7){
        const unsigned short* wpn = wbase + (size_t)(step + 1) * 16384;
        #pragma unroll
        for (int c = 0; c < 4; ++c){
          Pn[c] = *(const bf16x8*)(wpn + c * 128);        // gl(step+1)
          Qn[c] = *(const bf16x8*)(wpn + 2048 + c * 128); // gr(step+1)
        }
        #pragma unroll
        for (int m = 0; m < 2; ++m)
          afn[m] = *(const bf16x8*)&uni[(m * 16 + ln) * 256
                     + ((((step + 1) * 4 + g) ^ (ln & 7)) << 3)];
      }
      __builtin_amdgcn_s_setprio(1);
      #pragma unroll
      for (int m = 0; m < 2; ++m)
        #pragma unroll
        for (int c = 0; c < 4; ++c)
          acc[m][c] = __builtin_amdgcn_mfma_f32_16x16x32_bf16(af[m], P[c], acc[m][c], 0, 0, 0);
      #pragma unroll
      for (int m = 0; m < 2; ++m)
        #pragma unroll
        for (int c = 0; c < 4; ++c)
          acc[m][c + 4] = __builtin_amdgcn_mfma_f32_16x16x32_bf16(af[m], Q[c], acc[m][c + 4], 0, 0, 0);
      __builtin_amdgcn_s_setprio(0);
      if (step < 7){
        af[0] = afn[0]; af[1] = afn[1];
        #pragma unroll
        for (int c = 0; c < 4; ++c){ P[c] = Pn[c]; Q[c] = Qn[c]; }
      }
    }
  } else {
    for (int step = 0; step < 8; ++step){
      bf16x8 af[2], bfr[8];
      #pragma unroll
      for (int m = 0; m < 2; ++m){
        int row = m * 16 + ln;
        int chunk = step * 4 + g;
        af[m] = *(const bf16x8*)&uni[row * 256 + ((chunk ^ (row & 7)) << 3)];
      }
      #pragma unroll
      for (int c = 0; c < 4; ++c){
        int col = w * 64 + c * 16 + ln;
        #pragma unroll
        for (int j = 0; j < 8; ++j){
          bfr[c][j]     = (short)f2bf(Wl[(step * 32 + g * 8 + j) * 256 + col]);
          bfr[c + 4][j] = (short)f2bf(Wr[(step * 32 + g * 8 + j) * 256 + col]);
        }
      }
      #pragma unroll
      for (int m = 0; m < 2; ++m)
        #pragma unroll
        for (int c = 0; c < 8; ++c)
          acc[m][c] = __builtin_amdgcn_mfma_f32_16x16x32_bf16(af[m], bfr[c], acc[m][c], 0, 0, 0);
    }
  }

  // lane-role bits for the scatter reduce (per-thread constants)
  const bool b3 = (ln & 8) != 0;
  const bool b2 = (ln & 4) != 0;
  const bool b1 = (ln & 2) != 0;
  const bool bb0 = (ln & 1) != 0;

  // ---- attention compute for BOTH m (R21 verbatim; single barrier after)
  float hp[2][4][4];
  #pragma unroll
  for (int m = 0; m < 2; ++m){
    float p16[16];
    #pragma unroll
    for (int q = 0; q < 16; ++q) p16[q] = 0.f;
    #pragma unroll
    for (int c = 0; c < 4; ++c){
      f32x4 GL = acc[m][c];
      f32x4 GR = acc[m][c + 4];
      #pragma unroll
      for (int i = 0; i < 4; ++i)
        #pragma unroll
        for (int j = 0; j < 4; ++j){
          float x = GL[i] + GR[j];
          x = fmaxf(x, SLOPE * x);        // leaky_relu
          p16[i * 4 + j] = fmaf(x, av[c], p16[i * 4 + j]);
        }
    }
    // reduce-scatter across the 16-lane group: lane ln ends with e[ln]
    float r1[8];
    #pragma unroll
    for (int s = 0; s < 8; ++s){
      float snd = b3 ? p16[s] : p16[s + 8];
      float own = b3 ? p16[s + 8] : p16[s];
      r1[s] = own + __shfl_xor(snd, 8);
    }
    float r2[4];
    #pragma unroll
    for (int s = 0; s < 4; ++s){
      float snd = b2 ? r1[s] : r1[s + 4];
      float own = b2 ? r1[s + 4] : r1[s];
      r2[s] = own + __shfl_xor(snd, 4);
    }
    float r3[2];
    #pragma unroll
    for (int s = 0; s < 2; ++s){
      float snd = b1 ? r2[s] : r2[s + 2];
      float own = b1 ? r2[s + 2] : r2[s];
      r3[s] = own + __shfl_xor(snd, 2);
    }
    float E;
    {
      float snd = bb0 ? r3[0] : r3[1];
      float own = bb0 ? r3[1] : r3[0];
      E = own + __shfl_xor(snd, 1);
    }
    E += eb_s[ln];                        // q = ln -> eb[i*4+j] = eb_s[ln]

    // softmax over the 4-lane j-group
    float mx = fmaxf(E, __shfl_xor(E, 1));
    mx = fmaxf(mx, __shfl_xor(mx, 2));
    float p = __expf(E - mx);
    float sden = p + __shfl_xor(p, 1);
    sden += __shfl_xor(sden, 2);
    float a_own = p / sden;

    // regather all 16 alphas (group base = lane & 48)
    float al[16];
    #pragma unroll
    for (int q = 0; q < 16; ++q)
      al[q] = __shfl(a_own, (lane & 48) | q);

    // PV + LN partials
    float s1[4], s2[4];
    #pragma unroll
    for (int i = 0; i < 4; ++i){
      #pragma unroll
      for (int c = 0; c < 4; ++c){
        f32x4 GR = acc[m][c + 4];
        float v = al[i*4+0] * GR[0];
        v = fmaf(al[i*4+1], GR[1], v);
        v = fmaf(al[i*4+2], GR[2], v);
        v = fmaf(al[i*4+3], GR[3], v);
        hp[m][i][c] = v;
      }
      s1[i] = hp[m][i][0] + hp[m][i][1] + hp[m][i][2] + hp[m][i][3];
      s2[i] = fmaf(hp[m][i][0], hp[m][i][0],
              fmaf(hp[m][i][1], hp[m][i][1],
              fmaf(hp[m][i][2], hp[m][i][2], hp[m][i][3] * hp[m][i][3])));
    }
    #pragma unroll
    for (int mask = 1; mask <= 8; mask <<= 1)
      #pragma unroll
      for (int i = 0; i < 4; ++i){
        s1[i] += __shfl_xor(s1[i], mask);
        s2[i] += __shfl_xor(s2[i], mask);
      }
    #pragma unroll
    for (int i = 0; i < 4; ++i){
      int r = (m * 4 + g) * 4 + i;        // m=0: 0..15, m=1: 16..31 (disjoint)
      if (ln == 0){ red1[r * 4 + w] = s1[i]; red2[r * 4 + w] = s2[i]; }
    }
  }
  __syncthreads();                        // single barrier for both m

  // ---- epilogues (R19 verbatim)
  float gmr[4], btr[4];
  #pragma unroll
  for (int c = 0; c < 4; ++c){
    gmr[c] = gmw[w * 64 + c * 16 + ln];
    btr[c] = btw[w * 64 + c * 16 + ln];
  }
  #pragma unroll
  for (int m = 0; m < 2; ++m)
    #pragma unroll
    for (int i = 0; i < 4; ++i){
      int r = (m * 4 + g) * 4 + i;
      float4 v1 = *(const float4*)&red1[r * 4];
      float4 v2 = *(const float4*)&red2[r * 4];
      float s1 = (v1.x + v1.y) + (v1.z + v1.w);
      float s2 = (v2.x + v2.y) + (v2.z + v2.w);
      float mu = s1 * (1.f / 256.f);
      float var = s2 * (1.f / 256.f) - mu * mu;
      float inv = rsqrtf(var + LN_EPS);
      float* op = out + ((size_t)b0 * 4 + r) * 256 + w * 64 + ln;
      #pragma unroll
      for (int c = 0; c < 4; ++c)
        op[c * 16] = fmaf((hp[m][i][c] - mu) * inv, gmr[c], btr[c]);
    }
}

extern "C" void kernel_launch(void* const* d_in, const int* in_sizes, int n_in,
                              void* d_out, int out_size, void* d_ws, size_t ws_size,
                              hipStream_t stream){
  const float* h  = (const float*)d_in[0];
  const float* eb = (const float*)d_in[1];
  const float* Wl = (const float*)d_in[2];
  const float* Wr = (const float*)d_in[3];
  const float* a  = (const float*)d_in[4];
  const float* gm = (const float*)d_in[5];
  const float* bt = (const float*)d_in[6];
  float* out = (float*)d_out;
  (void)n_in; (void)out_size;

  int B = in_sizes[0] / 1024;        // (B, 4, 256) f32
  int nblk = B / 8;

  if (ws_size >= 262144){
    unsigned short* wbf = (unsigned short*)d_ws;
    wconv_kernel<<<64, 256, 0, stream>>>(Wl, Wr, wbf);
    gat_fused<true><<<nblk, 256, 0, stream>>>(h, eb, Wl, Wr, a, gm, bt, wbf, out);
  } else {
    gat_fused<false><<<nblk, 256, 0, stream>>>(h, eb, Wl, Wr, a, gm, bt, nullptr, out);
  }
}

// Round 24
// 84.088 us; speedup vs baseline: 1.0210x; 1.0210x over previous
//
#include <hip/hip_runtime.h>
#include <hip/hip_bf16.h>

typedef short bf16x8 __attribute__((ext_vector_type(8)));
typedef float f32x4 __attribute__((ext_vector_type(4)));

#define LN_EPS 1e-5f

// Native conversion: compiler fuses adjacent pairs to v_cvt_pk_bf16_f32 (m240).
__device__ __forceinline__ unsigned short f2bf(float f){
  __hip_bfloat16 b = __float2bfloat16(f);
  return *reinterpret_cast<unsigned short*>(&b);
}

// Verified W image (rounds 1..22):
// wbf[((s*4+g)*512 + c)*8 + j] = W[k = s*32+g*8+j][c]   (c<256: W_l, else W_r)
__global__ void wconv_kernel(const float* __restrict__ Wl,
                             const float* __restrict__ Wr,
                             unsigned short* __restrict__ wbf){
  int idx = blockIdx.x * 256 + threadIdx.x;   // 0..16383 : (s,g,c)
  int c = idx & 511;
  int gg = (idx >> 9) & 3;
  int s = idx >> 11;
  int k0 = s * 32 + gg * 8;
  const float* src = (c < 256) ? (Wl + c) : (Wr + (c - 256));
  bf16x8 v;
  #pragma unroll
  for (int j = 0; j < 8; ++j) v[j] = (short)f2bf(src[(k0 + j) * 256]);
  *(bf16x8*)&wbf[(size_t)idx * 8] = v;
}

// R22 verified base (84.5 us best; minwaves=2 — R23 showed minwaves=3 neutral),
// with LEAKY DECOMPOSITION in the e-init: leaky(x)*a = fma(0.6a,x) + fma(0.4a,|x|)
// (|x| is a free VOP3 input modifier) -> 3 ops/element vs 4 (add,mul,max,fma).
// Saves ~9% of VALU issue. 0.6x+0.4|x| == max(x,0.2x) exactly in reals; fp diff
// is ~1ulp association shift (4x threshold margin).
// NOTE: minwaves/EU >= 4 MISCOMPILES (R5/R6); =3 neutral (R23). Keep 2.
// NOTE: persistent/reg-prefetch-across-phases spills (R10,R18); no-LDS A-frags
// latency-bound (R20); kernel split loses to fusion (R16).
template<bool USE_WS>
__global__ __launch_bounds__(256, 2)
void gat_fused(const float* __restrict__ hin, const float* __restrict__ ebias,
               const float* __restrict__ Wl, const float* __restrict__ Wr,
               const float* __restrict__ avec, const float* __restrict__ gmw,
               const float* __restrict__ btw, const unsigned short* __restrict__ wbf,
               float* __restrict__ out){
  __shared__ __align__(16) unsigned short uni[8192];    // h-tile [32][256] bf16, 16KB
  __shared__ float red1[128], red2[128];                // [row][wave] LN partials
  __shared__ float eb_s[16];

  const int t = threadIdx.x;
  const int lane = t & 63;
  const int w = t >> 6;
  const int b0 = blockIdx.x * 8;
  const int g = lane >> 4;
  const int ln = lane & 15;

  float av6[4], av4[4];
  #pragma unroll
  for (int c = 0; c < 4; ++c){
    float a = avec[w * 64 + c * 16 + ln];
    av6[c] = 0.6f * a;
    av4[c] = 0.4f * a;
  }
  if (t < 16) eb_s[t] = ebias[t];

  // ---- stage h tile (32 rows x 256 k) f32->bf16, XOR-swizzled (verified R4)
  {
    const float* hb = hin + (size_t)b0 * 1024;
    #pragma unroll
    for (int it = 0; it < 4; ++it){
      int q = it * 256 + t;              // 16B-chunk id, 1024 total
      int row = q >> 5;
      int c = q & 31;
      const float* src = hb + row * 256 + c * 8;
      float4 f0 = *(const float4*)src;
      float4 f1 = *(const float4*)(src + 4);
      bf16x8 v;
      v[0]=(short)f2bf(f0.x); v[1]=(short)f2bf(f0.y); v[2]=(short)f2bf(f0.z); v[3]=(short)f2bf(f0.w);
      v[4]=(short)f2bf(f1.x); v[5]=(short)f2bf(f1.y); v[6]=(short)f2bf(f1.z); v[7]=(short)f2bf(f1.w);
      *(bf16x8*)&uni[row * 256 + ((c ^ (row & 7)) << 3)] = v;
    }
  }
  __syncthreads();

  f32x4 acc[2][8];
  #pragma unroll
  for (int m = 0; m < 2; ++m)
    #pragma unroll
    for (int c = 0; c < 8; ++c)
      acc[m][c] = (f32x4){0.f, 0.f, 0.f, 0.f};

  // ---- pipelined K loop, full-step prefetch for P and Q (R22 verbatim)
  if constexpr (USE_WS){
    const unsigned short* wbase = wbf + (size_t)g * 4096 + (size_t)(w * 64 + ln) * 8;
    bf16x8 af[2], afn[2], P[4], Q[4], Pn[4], Qn[4];
    #pragma unroll
    for (int m = 0; m < 2; ++m)
      af[m] = *(const bf16x8*)&uni[(m * 16 + ln) * 256 + ((g ^ (ln & 7)) << 3)];
    #pragma unroll
    for (int c = 0; c < 4; ++c){
      P[c] = *(const bf16x8*)(wbase + c * 128);           // gl(0)
      Q[c] = *(const bf16x8*)(wbase + 2048 + c * 128);    // gr(0)
    }

    #pragma unroll
    for (int step = 0; step < 8; ++step){
      if (step < 7){
        const unsigned short* wpn = wbase + (size_t)(step + 1) * 16384;
        #pragma unroll
        for (int c = 0; c < 4; ++c){
          Pn[c] = *(const bf16x8*)(wpn + c * 128);        // gl(step+1)
          Qn[c] = *(const bf16x8*)(wpn + 2048 + c * 128); // gr(step+1)
        }
        #pragma unroll
        for (int m = 0; m < 2; ++m)
          afn[m] = *(const bf16x8*)&uni[(m * 16 + ln) * 256
                     + ((((step + 1) * 4 + g) ^ (ln & 7)) << 3)];
      }
      __builtin_amdgcn_s_setprio(1);
      #pragma unroll
      for (int m = 0; m < 2; ++m)
        #pragma unroll
        for (int c = 0; c < 4; ++c)
          acc[m][c] = __builtin_amdgcn_mfma_f32_16x16x32_bf16(af[m], P[c], acc[m][c], 0, 0, 0);
      #pragma unroll
      for (int m = 0; m < 2; ++m)
        #pragma unroll
        for (int c = 0; c < 4; ++c)
          acc[m][c + 4] = __builtin_amdgcn_mfma_f32_16x16x32_bf16(af[m], Q[c], acc[m][c + 4], 0, 0, 0);
      __builtin_amdgcn_s_setprio(0);
      if (step < 7){
        af[0] = afn[0]; af[1] = afn[1];
        #pragma unroll
        for (int c = 0; c < 4; ++c){ P[c] = Pn[c]; Q[c] = Qn[c]; }
      }
    }
  } else {
    for (int step = 0; step < 8; ++step){
      bf16x8 af[2], bfr[8];
      #pragma unroll
      for (int m = 0; m < 2; ++m){
        int row = m * 16 + ln;
        int chunk = step * 4 + g;
        af[m] = *(const bf16x8*)&uni[row * 256 + ((chunk ^ (row & 7)) << 3)];
      }
      #pragma unroll
      for (int c = 0; c < 4; ++c){
        int col = w * 64 + c * 16 + ln;
        #pragma unroll
        for (int j = 0; j < 8; ++j){
          bfr[c][j]     = (short)f2bf(Wl[(step * 32 + g * 8 + j) * 256 + col]);
          bfr[c + 4][j] = (short)f2bf(Wr[(step * 32 + g * 8 + j) * 256 + col]);
        }
      }
      #pragma unroll
      for (int m = 0; m < 2; ++m)
        #pragma unroll
        for (int c = 0; c < 8; ++c)
          acc[m][c] = __builtin_amdgcn_mfma_f32_16x16x32_bf16(af[m], bfr[c], acc[m][c], 0, 0, 0);
    }
  }

  // lane-role bits for the scatter reduce (per-thread constants)
  const bool b3 = (ln & 8) != 0;
  const bool b2 = (ln & 4) != 0;
  const bool b1 = (ln & 2) != 0;
  const bool bb0 = (ln & 1) != 0;

  // ---- attention compute for BOTH m (single barrier after)
  float hp[2][4][4];
  #pragma unroll
  for (int m = 0; m < 2; ++m){
    float p16[16];
    #pragma unroll
    for (int q = 0; q < 16; ++q) p16[q] = 0.f;
    #pragma unroll
    for (int c = 0; c < 4; ++c){
      f32x4 GL = acc[m][c];
      f32x4 GR = acc[m][c + 4];
      #pragma unroll
      for (int i = 0; i < 4; ++i)
        #pragma unroll
        for (int j = 0; j < 4; ++j){
          float x = GL[i] + GR[j];
          // leaky(x)*a = 0.6a*x + 0.4a*|x|  (|x| = free VOP3 input modifier)
          float tacc = fmaf(av6[c], x, p16[i * 4 + j]);
          p16[i * 4 + j] = fmaf(av4[c], fabsf(x), tacc);
        }
    }
    // reduce-scatter across the 16-lane group: lane ln ends with e[ln]
    float r1[8];
    #pragma unroll
    for (int s = 0; s < 8; ++s){
      float snd = b3 ? p16[s] : p16[s + 8];
      float own = b3 ? p16[s + 8] : p16[s];
      r1[s] = own + __shfl_xor(snd, 8);
    }
    float r2[4];
    #pragma unroll
    for (int s = 0; s < 4; ++s){
      float snd = b2 ? r1[s] : r1[s + 4];
      float own = b2 ? r1[s + 4] : r1[s];
      r2[s] = own + __shfl_xor(snd, 4);
    }
    float r3[2];
    #pragma unroll
    for (int s = 0; s < 2; ++s){
      float snd = b1 ? r2[s] : r2[s + 2];
      float own = b1 ? r2[s + 2] : r2[s];
      r3[s] = own + __shfl_xor(snd, 2);
    }
    float E;
    {
      float snd = bb0 ? r3[0] : r3[1];
      float own = bb0 ? r3[1] : r3[0];
      E = own + __shfl_xor(snd, 1);
    }
    E += eb_s[ln];                        // q = ln -> eb[i*4+j] = eb_s[ln]

    // softmax over the 4-lane j-group
    float mx = fmaxf(E, __shfl_xor(E, 1));
    mx = fmaxf(mx, __shfl_xor(mx, 2));
    float p = __expf(E - mx);
    float sden = p + __shfl_xor(p, 1);
    sden += __shfl_xor(sden, 2);
    float a_own = p / sden;

    // regather all 16 alphas (group base = lane & 48)
    float al[16];
    #pragma unroll
    for (int q = 0; q < 16; ++q)
      al[q] = __shfl(a_own, (lane & 48) | q);

    // PV + LN partials
    float s1[4], s2[4];
    #pragma unroll
    for (int i = 0; i < 4; ++i){
      #pragma unroll
      for (int c = 0; c < 4; ++c){
        f32x4 GR = acc[m][c + 4];
        float v = al[i*4+0] * GR[0];
        v = fmaf(al[i*4+1], GR[1], v);
        v = fmaf(al[i*4+2], GR[2], v);
        v = fmaf(al[i*4+3], GR[3], v);
        hp[m][i][c] = v;
      }
      s1[i] = hp[m][i][0] + hp[m][i][1] + hp[m][i][2] + hp[m][i][3];
      s2[i] = fmaf(hp[m][i][0], hp[m][i][0],
              fmaf(hp[m][i][1], hp[m][i][1],
              fmaf(hp[m][i][2], hp[m][i][2], hp[m][i][3] * hp[m][i][3])));
    }
    #pragma unroll
    for (int mask = 1; mask <= 8; mask <<= 1)
      #pragma unroll
      for (int i = 0; i < 4; ++i){
        s1[i] += __shfl_xor(s1[i], mask);
        s2[i] += __shfl_xor(s2[i], mask);
      }
    #pragma unroll
    for (int i = 0; i < 4; ++i){
      int r = (m * 4 + g) * 4 + i;        // m=0: 0..15, m=1: 16..31 (disjoint)
      if (ln == 0){ red1[r * 4 + w] = s1[i]; red2[r * 4 + w] = s2[i]; }
    }
  }
  __syncthreads();                        // single barrier for both m

  // ---- epilogues (R19 verbatim)
  float gmr[4], btr[4];
  #pragma unroll
  for (int c = 0; c < 4; ++c){
    gmr[c] = gmw[w * 64 + c * 16 + ln];
    btr[c] = btw[w * 64 + c * 16 + ln];
  }
  #pragma unroll
  for (int m = 0; m < 2; ++m)
    #pragma unroll
    for (int i = 0; i < 4; ++i){
      int r = (m * 4 + g) * 4 + i;
      float4 v1 = *(const float4*)&red1[r * 4];
      float4 v2 = *(const float4*)&red2[r * 4];
      float s1 = (v1.x + v1.y) + (v1.z + v1.w);
      float s2 = (v2.x + v2.y) + (v2.z + v2.w);
      float mu = s1 * (1.f / 256.f);
      float var = s2 * (1.f / 256.f) - mu * mu;
      float inv = rsqrtf(var + LN_EPS);
      float* op = out + ((size_t)b0 * 4 + r) * 256 + w * 64 + ln;
      #pragma unroll
      for (int c = 0; c < 4; ++c)
        op[c * 16] = fmaf((hp[m][i][c] - mu) * inv, gmr[c], btr[c]);
    }
}

extern "C" void kernel_launch(void* const* d_in, const int* in_sizes, int n_in,
                              void* d_out, int out_size, void* d_ws, size_t ws_size,
                              hipStream_t stream){
  const float* h  = (const float*)d_in[0];
  const float* eb = (const float*)d_in[1];
  const float* Wl = (const float*)d_in[2];
  const float* Wr = (const float*)d_in[3];
  const float* a  = (const float*)d_in[4];
  const float* gm = (const float*)d_in[5];
  const float* bt = (const float*)d_in[6];
  float* out = (float*)d_out;
  (void)n_in; (void)out_size;

  int B = in_sizes[0] / 1024;        // (B, 4, 256) f32
  int nblk = B / 8;

  if (ws_size >= 262144){
    unsigned short* wbf = (unsigned short*)d_ws;
    wconv_kernel<<<64, 256, 0, stream>>>(Wl, Wr, wbf);
    gat_fused<true><<<nblk, 256, 0, stream>>>(h, eb, Wl, Wr, a, gm, bt, wbf, out);
  } else {
    gat_fused<false><<<nblk, 256, 0, stream>>>(h, eb, Wl, Wr, a, gm, bt, nullptr, out);
  }
}